// Round 6
// baseline (230.091 us; speedup 1.0000x reference)
//
#include <hip/hip_runtime.h>
#include <hip/hip_bf16.h>

// Problem dims (fixed by setup_inputs)
#define Mdim 8192
#define Ndim 2048
#define Kdim 2048
#define NT   32      // number of K-tiles (Kdim / 64)

constexpr float kMin = -128.0f;
constexpr float kMax = 127.99609375f;
constexpr float kScale = 256.0f;
constexpr float kInvScale = 1.0f / 256.0f;
constexpr float kEps = 1e-5f;

typedef __attribute__((ext_vector_type(8))) short short8;
typedef __attribute__((ext_vector_type(4))) float f32x4;

__device__ __forceinline__ float fpq(float x) {
    x = fminf(fmaxf(x, kMin), kMax);
    return rintf(x * kScale) * kInvScale;   // round-half-to-even, matches jnp.round
}

__device__ __forceinline__ unsigned short f2bf(float f) {
    union { __hip_bfloat16 h; unsigned short u; } cv;
    cv.h = __float2bfloat16(f);             // RNE
    return cv.u;
}

__device__ __forceinline__ void gload_lds16(const void* g, void* l) {
    __builtin_amdgcn_global_load_lds(
        (const __attribute__((address_space(1))) unsigned int*)g,
        (__attribute__((address_space(3))) unsigned int*)l,
        16, 0, 0);
}

__device__ __forceinline__ void phase_barrier() {
    __builtin_amdgcn_sched_barrier(0);
    __builtin_amdgcn_s_barrier();
    __builtin_amdgcn_sched_barrier(0);
    asm volatile("" ::: "memory");
}

__device__ __forceinline__ void wait_vmcnt4() {
    __builtin_amdgcn_sched_barrier(0);
    asm volatile("s_waitcnt vmcnt(4)" ::: "memory");
    __builtin_amdgcn_sched_barrier(0);
}

// ---------------------------------------------------------------------------
// Fused prep: zero stats (block 0), quantize w -> bf16 (blocks 0..1023),
// convert x -> bf16 (blocks 1024..3071).
__global__ void fpbn_prep(const float* __restrict__ w,
                          unsigned short* __restrict__ wb,
                          const float* __restrict__ x,
                          unsigned short* __restrict__ xb,
                          float* __restrict__ stats) {
    const int b = blockIdx.x;
    if (b == 0) {
        float4 z = {0.f, 0.f, 0.f, 0.f};
        for (int i = threadIdx.x; i < 1024; i += 256)   // 4096 floats
            ((float4*)stats)[i] = z;
    }
    if (b < 1024) {
        const int n4 = Ndim * Kdim / 4;
        for (int i = b * 256 + threadIdx.x; i < n4; i += 1024 * 256) {
            float4 v = ((const float4*)w)[i];
            ushort4 o;
            o.x = f2bf(fpq(v.x));
            o.y = f2bf(fpq(v.y));
            o.z = f2bf(fpq(v.z));
            o.w = f2bf(fpq(v.w));
            ((ushort4*)wb)[i] = o;
        }
    } else {
        const int n8 = Mdim * Kdim / 8;
        for (int i = (b - 1024) * 256 + threadIdx.x; i < n8; i += 2048 * 256) {
            float4 p = ((const float4*)x)[2 * i];
            float4 q = ((const float4*)x)[2 * i + 1];
            uint4 o;
            o.x = (unsigned)f2bf(p.x) | ((unsigned)f2bf(p.y) << 16);
            o.y = (unsigned)f2bf(p.z) | ((unsigned)f2bf(p.w) << 16);
            o.z = (unsigned)f2bf(q.x) | ((unsigned)f2bf(q.y) << 16);
            o.w = (unsigned)f2bf(q.z) | ((unsigned)f2bf(q.w) << 16);
            ((uint4*)xb)[i] = o;
        }
    }
}

// ---------------------------------------------------------------------------
// 256x256x(BK=64) bf16 MFMA GEMM, overlapped 4-cluster schedule.
// 8 waves (2Mx4N), 512 threads. LDS 128 KiB XOR-swizzled (row&7)<<4.
// Per tile: C1(Af,Bf0) | bar | S2(Bf1 first, Af2 under C2) C2 | bar | C3 | bar
// | vmcnt(4) bar | C4(Af2,Bf0-reused). 4 barriers, 24 ds_reads/wave/tile.
// XCD chunking: bm=(blk&7)*4+(blk>>6), bn=(blk>>3)&7 -> 4bm x 8bn per XCD.
// OUT16: y stored i16*256 in TILED layout (coalesced 128B lines):
//   idx = ((((blk*8+w)*4+n)*32 + m*4+j)*64 + lane
template <bool OUT16>
__global__ __launch_bounds__(512, 2) void fpbn_gemm8(
    const unsigned short* __restrict__ xb, const unsigned short* __restrict__ wb,
    const float* __restrict__ bias, short* __restrict__ y16,
    float* __restrict__ yf, float* __restrict__ colsum,
    float* __restrict__ colsumsq) {

    __shared__ unsigned short lds[65536];   // 128 KiB, 8 slots of 8192 elems

    const int t    = threadIdx.x;
    const int lane = t & 63;
    const int w    = t >> 6;        // 0..7
    const int wm   = w >> 2;        // 0..1  (M half of 256)
    const int wn   = w & 3;         // 0..3  (N quarter)

    const int blk  = blockIdx.x;
    const int bm   = (blk & 7) * 4 + (blk >> 6);    // 0..31
    const int bn   = (blk >> 3) & 7;                // 0..7
    const int row0 = bm * 256;
    const int col0 = bn * 256;

    // ---- staging source addresses (linear LDS dest, inverse-swizzled src) ----
    const int roff = t >> 3;                        // row within half: 0..63
    const int colE = ((t & 7) ^ (roff & 7)) * 8;    // swizzle-compensated col (elems)
    const unsigned short* srcA[2] = {
        xb + (size_t)(row0 +   0 + roff) * Kdim + colE,
        xb + (size_t)(row0 + 128 + roff) * Kdim + colE };
    const unsigned short* srcB[2] = {
        wb + (size_t)(col0 +   0 + roff) * Kdim + colE,
        wb + (size_t)(col0 + 128 + roff) * Kdim + colE };
    const int t8 = t * 8;

    // ---- swizzled read-side per-lane constants ----
    const int x3    = lane & 7;
    const int xk    = x3 >> 2;                 // flips kk-select (bit6 of XOR)
    const int xh    = x3 & 3;                  // flips hi-select (bits 4-5)
    const int hi    = lane >> 4;
    const int rb2   = (lane & 15) * 64 + ((hi ^ xh) * 8);
    const int k0off = xk * 32;                 // elem offset of logical kk=0
    const int k1off = 32 - k0off;              // logical kk=1
    const int bnoff = (wn & 1) * 4096;

#define STAGE(BUF_, S_, OP_, HALF_) do {                                      \
        int ss_ = (S_) < NT ? (S_) : (S_) - 2;  /* tail clamp, keeps parity */\
        const unsigned short* sp_ = (OP_ ? srcB : srcA)[HALF_] + ss_ * 64;    \
        unsigned short* dp_ =                                                 \
            &lds[(((BUF_) * 4 + (OP_) * 2 + (HALF_)) << 13) + t8];            \
        gload_lds16(sp_, dp_);                                                \
        gload_lds16(sp_ + (size_t)64 * Kdim, dp_ + 4096);                     \
    } while (0)

#define READA(BUF_, M_, KOFF_) \
    (*(const short8*)&lds[(((BUF_) * 4 + wm) << 13) + rb2 + (M_) * 1024 + (KOFF_)])
#define READB(BUF_, N_, KOFF_) \
    (*(const short8*)&lds[(((BUF_) * 4 + 2 + (wn >> 1)) << 13) + bnoff + rb2 + (N_) * 1024 + (KOFF_)])
#define MFMA_(A_, B_, C_) \
    C_ = __builtin_amdgcn_mfma_f32_16x16x32_bf16(A_, B_, C_, 0, 0, 0)

    f32x4 acc[8][4] = {};

    // prologue: tile0 A+B (buf0), tile1 A (buf1) = 6 stages; drain; barrier
    STAGE(0, 0, 0, 0); STAGE(0, 0, 0, 1); STAGE(0, 0, 1, 0); STAGE(0, 0, 1, 1);
    STAGE(1, 1, 0, 0); STAGE(1, 1, 0, 1);
    __builtin_amdgcn_sched_barrier(0);
    asm volatile("s_waitcnt vmcnt(0)" ::: "memory");
    __builtin_amdgcn_sched_barrier(0);
    phase_barrier();

#define KTILE(BUF_, ST1_, ST2_, ST3_, ST4_) do {                              \
        /* S1: Bf0 + Af; C1 */                                                \
        _Pragma("unroll") for (int n = 0; n < 2; ++n) {                       \
            Bf0[n][0] = READB(BUF_, n, k0off);                                \
            Bf0[n][1] = READB(BUF_, n, k1off); }                              \
        _Pragma("unroll") for (int m = 0; m < 4; ++m) {                       \
            Af[m][0] = READA(BUF_, m, k0off);                                 \
            Af[m][1] = READA(BUF_, m, k1off); }                               \
        ST1_;                                                                 \
        __builtin_amdgcn_s_setprio(1);                                        \
        _Pragma("unroll") for (int m = 0; m < 4; ++m)                         \
        _Pragma("unroll") for (int n = 0; n < 2; ++n) {                       \
            MFMA_(Af[m][0], Bf0[n][0], acc[m][n]);                            \
            MFMA_(Af[m][1], Bf0[n][1], acc[m][n]); }                          \
        __builtin_amdgcn_s_setprio(0);                                        \
        phase_barrier();                                                      \
        /* S2: Bf1 first (C2 waits only these), Af2 overlaps C2; C2 */        \
        _Pragma("unroll") for (int n = 0; n < 2; ++n) {                       \
            Bf1[n][0] = READB(BUF_, n + 2, k0off);                            \
            Bf1[n][1] = READB(BUF_, n + 2, k1off); }                          \
        _Pragma("unroll") for (int m = 0; m < 4; ++m) {                       \
            Af2[m][0] = READA(BUF_, m + 4, k0off);                            \
            Af2[m][1] = READA(BUF_, m + 4, k1off); }                          \
        ST2_;                                                                 \
        __builtin_amdgcn_s_setprio(1);                                        \
        _Pragma("unroll") for (int m = 0; m < 4; ++m)                         \
        _Pragma("unroll") for (int n = 0; n < 2; ++n) {                       \
            MFMA_(Af[m][0], Bf1[n][0], acc[m][n + 2]);                        \
            MFMA_(Af[m][1], Bf1[n][1], acc[m][n + 2]); }                      \
        __builtin_amdgcn_s_setprio(0);                                        \
        phase_barrier();                                                      \
        /* C3 */                                                              \
        ST3_;                                                                 \
        __builtin_amdgcn_s_setprio(1);                                        \
        _Pragma("unroll") for (int m = 0; m < 4; ++m)                         \
        _Pragma("unroll") for (int n = 0; n < 2; ++n) {                       \
            MFMA_(Af2[m][0], Bf1[n][0], acc[m + 4][n + 2]);                   \
            MFMA_(Af2[m][1], Bf1[n][1], acc[m + 4][n + 2]); }                 \
        __builtin_amdgcn_s_setprio(0);                                        \
        phase_barrier();                                                      \
        /* C4: reuse Bf0 regs (no re-read) */                                 \
        ST4_;                                                                 \
        wait_vmcnt4();                                                        \
        phase_barrier();                                                      \
        __builtin_amdgcn_s_setprio(1);                                        \
        _Pragma("unroll") for (int m = 0; m < 4; ++m)                         \
        _Pragma("unroll") for (int n = 0; n < 2; ++n) {                       \
            MFMA_(Af2[m][0], Bf0[n][0], acc[m + 4][n]);                       \
            MFMA_(Af2[m][1], Bf0[n][1], acc[m + 4][n]); }                     \
        __builtin_amdgcn_s_setprio(0);                                        \
    } while (0)

#pragma unroll 1
    for (int it = 0; it < NT / 2; ++it) {
        const int s0 = 2 * it;
        short8 Af[4][2], Af2[4][2], Bf0[2][2], Bf1[2][2];
        KTILE(0, STAGE(1, s0 + 1, 1, 0), STAGE(1, s0 + 1, 1, 1),
                 STAGE(0, s0 + 2, 0, 0), STAGE(0, s0 + 2, 0, 1));
        KTILE(1, STAGE(0, s0 + 2, 1, 0), STAGE(0, s0 + 2, 1, 1),
                 STAGE(1, s0 + 3, 0, 0), STAGE(1, s0 + 3, 0, 1));
    }

    // Epilogue. C/D layout: col = lane&15, row = (lane>>4)*4 + j
#pragma unroll
    for (int n = 0; n < 4; ++n) {
        const int col = col0 + wn * 64 + n * 16 + (lane & 15);
        const float qb = fpq(bias[col]);
        float s = 0.0f, s2 = 0.0f;
#pragma unroll
        for (int m = 0; m < 8; ++m) {
            const int rowb = row0 + wm * 128 + m * 16 + ((lane >> 4) * 4);
#pragma unroll
            for (int j = 0; j < 4; ++j) {
                float v = fpq(acc[m][n][j]);
                v = fpq(v + qb);
                if constexpr (OUT16) {
                    // tiled layout: 128B-dense lines
                    size_t idx = ((((size_t)blk * 8 + w) * 4 + n) * 32
                                  + m * 4 + j) * 64 + lane;
                    y16[idx] = (short)(v * 256.0f);
                } else {
                    yf[(size_t)(rowb + j) * Ndim + col] = v;
                }
                s += v;
                s2 += v * v;
            }
        }
        s  += __shfl_xor(s, 16, 64);  s  += __shfl_xor(s, 32, 64);
        s2 += __shfl_xor(s2, 16, 64); s2 += __shfl_xor(s2, 32, 64);
        if (lane < 16) {
            atomicAdd(&colsum[col], s);
            atomicAdd(&colsumsq[col], s2);
        }
    }
#undef STAGE
#undef READA
#undef READB
#undef MFMA_
#undef KTILE
}

// ---------------------------------------------------------------------------
__global__ void fpbn_finalize(const float* __restrict__ colsum,
                              const float* __restrict__ colsumsq,
                              const float* __restrict__ gamma,
                              const float* __restrict__ beta,
                              float* __restrict__ a, float* __restrict__ b) {
    int i = blockIdx.x * blockDim.x + threadIdx.x;
    if (i < Ndim) {
        float mean = colsum[i] * (1.0f / Mdim);
        float var  = colsumsq[i] * (1.0f / Mdim) - mean * mean;
        float inv  = 1.0f / sqrtf(var + kEps);
        float ai   = gamma[i] * inv;
        a[i] = ai;
        b[i] = beta[i] - mean * ai;
    }
}

// BN apply + final quantize: tiled i16 y -> row-major f32 out.
// Thread g handles row r = g>>8, cols c..c+7 (c = (g&255)*8).
__global__ void fpbn_apply16(const short* __restrict__ y16,
                             float* __restrict__ out,
                             const float* __restrict__ a,
                             const float* __restrict__ b, int ngroups) {
    int tid = blockIdx.x * blockDim.x + threadIdx.x;
    int stride = gridDim.x * blockDim.x;
    for (int g = tid; g < ngroups; g += stride) {
        const int r  = g >> 8;
        const int c  = (g & 255) * 8;
        const int bm = r >> 8, wm = (r >> 7) & 1, m = (r >> 4) & 7,
                  hi = (r >> 2) & 3, j = r & 3;
        const int bn = c >> 8, wn = (c >> 6) & 3, n = (c >> 4) & 3,
                  lane = hi * 16 + (c & 15);
        const int blk = (bm >> 2) | (bn << 3) | ((bm & 3) << 6);
        const int w   = wm * 4 + wn;
        const size_t idx = ((((size_t)blk * 8 + w) * 4 + n) * 32
                            + m * 4 + j) * 64 + lane;
        int4 raw = *(const int4*)(y16 + idx);      // 8 shorts, 16B aligned
        const short* sp = (const short*)&raw;
        float4 a0 = *(const float4*)&a[c], a1 = *(const float4*)&a[c + 4];
        float4 b0 = *(const float4*)&b[c], b1 = *(const float4*)&b[c + 4];
        float4 o0, o1;
        o0.x = fpq(fmaf(a0.x, (float)sp[0] * kInvScale, b0.x));
        o0.y = fpq(fmaf(a0.y, (float)sp[1] * kInvScale, b0.y));
        o0.z = fpq(fmaf(a0.z, (float)sp[2] * kInvScale, b0.z));
        o0.w = fpq(fmaf(a0.w, (float)sp[3] * kInvScale, b0.w));
        o1.x = fpq(fmaf(a1.x, (float)sp[4] * kInvScale, b1.x));
        o1.y = fpq(fmaf(a1.y, (float)sp[5] * kInvScale, b1.y));
        o1.z = fpq(fmaf(a1.z, (float)sp[6] * kInvScale, b1.z));
        o1.w = fpq(fmaf(a1.w, (float)sp[7] * kInvScale, b1.w));
        float* op = out + (size_t)r * Ndim + c;
        ((float4*)op)[0] = o0;
        ((float4*)op)[1] = o1;
    }
}

// BN apply + final quantize, f32 y in-place (fallback path)
__global__ void fpbn_apply(float* __restrict__ y,
                           const float* __restrict__ a,
                           const float* __restrict__ b, int n4) {
    int i = blockIdx.x * blockDim.x + threadIdx.x;
    int stride = gridDim.x * blockDim.x;
    for (; i < n4; i += stride) {
        float4 v = ((float4*)y)[i];
        int cb = (i * 4) & (Ndim - 1);
        float4 av = *(const float4*)&a[cb];
        float4 bv = *(const float4*)&b[cb];
        v.x = fpq(fmaf(av.x, v.x, bv.x));
        v.y = fpq(fmaf(av.y, v.y, bv.y));
        v.z = fpq(fmaf(av.z, v.z, bv.z));
        v.w = fpq(fmaf(av.w, v.w, bv.w));
        ((float4*)y)[i] = v;
    }
}

// ---------------------------------------------------------------------------
extern "C" void kernel_launch(void* const* d_in, const int* in_sizes, int n_in,
                              void* d_out, int out_size, void* d_ws, size_t ws_size,
                              hipStream_t stream) {
    const float* x      = (const float*)d_in[0];
    const float* weight = (const float*)d_in[1];
    const float* bias   = (const float*)d_in[2];
    const float* gamma  = (const float*)d_in[3];
    const float* beta   = (const float*)d_in[4];
    float* out = (float*)d_out;

    // ws: wb bf16 [8MB] | stats [64KB] | xb bf16 [32MB] | y16 [32MB optional]
    char* ws = (char*)d_ws;
    unsigned short* wb = (unsigned short*)ws;
    const size_t wbBytes = (size_t)Ndim * Kdim * 2;
    float* colsum   = (float*)(ws + wbBytes);
    float* colsumsq = colsum + Ndim;
    float* aArr     = colsum + 2 * Ndim;
    float* bArr     = colsum + 3 * Ndim;
    const size_t xbOff = wbBytes + 65536;
    unsigned short* xb = (unsigned short*)(ws + xbOff);
    const size_t xbBytes  = (size_t)Mdim * Kdim * 2;
    const size_t y16Off   = xbOff + xbBytes;
    short* y16 = (short*)(ws + y16Off);
    const size_t need16 = y16Off + (size_t)Mdim * Ndim * 2;   // ~72.1 MB

    fpbn_prep<<<3072, 256, 0, stream>>>(weight, wb, x, xb, colsum);

    if (ws_size >= need16) {
        fpbn_gemm8<true><<<(Mdim / 256) * (Ndim / 256), 512, 0, stream>>>(
            xb, wb, bias, y16, nullptr, colsum, colsumsq);
        fpbn_finalize<<<(Ndim + 255) / 256, 256, 0, stream>>>(
            colsum, colsumsq, gamma, beta, aArr, bArr);
        fpbn_apply16<<<2048, 256, 0, stream>>>(y16, out, aArr, bArr,
                                               Mdim * Ndim / 8);
    } else {
        fpbn_gemm8<false><<<(Mdim / 256) * (Ndim / 256), 512, 0, stream>>>(
            xb, wb, bias, nullptr, out, colsum, colsumsq);
        fpbn_finalize<<<(Ndim + 255) / 256, 256, 0, stream>>>(
            colsum, colsumsq, gamma, beta, aArr, bArr);
        fpbn_apply<<<2048, 256, 0, stream>>>(out, aArr, bArr, Mdim * Ndim / 4);
    }
}

// Round 8
// 215.530 us; speedup vs baseline: 1.0676x; 1.0676x over previous
//
#include <hip/hip_runtime.h>
#include <hip/hip_bf16.h>

// Problem dims (fixed by setup_inputs)
#define Mdim 8192
#define Ndim 2048
#define Kdim 2048
#define NT   32      // number of K-tiles (Kdim / 64)

constexpr float kMin = -128.0f;
constexpr float kMax = 127.99609375f;
constexpr float kScale = 256.0f;
constexpr float kInvScale = 1.0f / 256.0f;
constexpr float kEps = 1e-5f;

typedef __attribute__((ext_vector_type(8))) short short8;
typedef __attribute__((ext_vector_type(4))) float f32x4;

__device__ __forceinline__ float fpq(float x) {
    x = fminf(fmaxf(x, kMin), kMax);
    return rintf(x * kScale) * kInvScale;   // round-half-to-even, matches jnp.round
}

__device__ __forceinline__ unsigned short f2bf(float f) {
    union { __hip_bfloat16 h; unsigned short u; } cv;
    cv.h = __float2bfloat16(f);             // RNE
    return cv.u;
}

__device__ __forceinline__ void gload_lds16(const void* g, void* l) {
    __builtin_amdgcn_global_load_lds(
        (const __attribute__((address_space(1))) unsigned int*)g,
        (__attribute__((address_space(3))) unsigned int*)l,
        16, 0, 0);
}

// ---------------------------------------------------------------------------
// Fused prep: zero stats (block 0), quantize w -> bf16 (blocks 0..1023),
// convert x -> bf16 (blocks 1024..3071).
__global__ void fpbn_prep(const float* __restrict__ w,
                          unsigned short* __restrict__ wb,
                          const float* __restrict__ x,
                          unsigned short* __restrict__ xb,
                          float* __restrict__ stats) {
    const int b = blockIdx.x;
    if (b == 0) {
        float4 z = {0.f, 0.f, 0.f, 0.f};
        for (int i = threadIdx.x; i < 1024; i += 256)   // 4096 floats
            ((float4*)stats)[i] = z;
    }
    if (b < 1024) {
        const int n4 = Ndim * Kdim / 4;
        for (int i = b * 256 + threadIdx.x; i < n4; i += 1024 * 256) {
            float4 v = ((const float4*)w)[i];
            ushort4 o;
            o.x = f2bf(fpq(v.x));
            o.y = f2bf(fpq(v.y));
            o.z = f2bf(fpq(v.z));
            o.w = f2bf(fpq(v.w));
            ((ushort4*)wb)[i] = o;
        }
    } else {
        const int n8 = Mdim * Kdim / 8;
        for (int i = (b - 1024) * 256 + threadIdx.x; i < n8; i += 2048 * 256) {
            float4 p = ((const float4*)x)[2 * i];
            float4 q = ((const float4*)x)[2 * i + 1];
            uint4 o;
            o.x = (unsigned)f2bf(p.x) | ((unsigned)f2bf(p.y) << 16);
            o.y = (unsigned)f2bf(p.z) | ((unsigned)f2bf(p.w) << 16);
            o.z = (unsigned)f2bf(q.x) | ((unsigned)f2bf(q.y) << 16);
            o.w = (unsigned)f2bf(q.z) | ((unsigned)f2bf(q.w) << 16);
            ((uint4*)xb)[i] = o;
        }
    }
}

// ---------------------------------------------------------------------------
// 256x256x(BK=64) bf16 MFMA GEMM, m201 8-phase skeleton, 1.5-tile-deep
// staging pipeline. 8 waves (2Mx4N), 512 threads, LDS 128 KiB XOR-swizzled.
//
// LEDGER (all waves read ALL 4 half-tile slots each phase, so tile t must be
// fully retired before P1(t)): stage SA1(t+1)@P1(t), SB0/SB1(t+2)@P3(t),
// SA0(t+2)@P4(t); single gate vmcnt(6) at P4(t) retires through SA1(t+1)
// (issued 3 phases earlier -> near-free), leaves {B0,B1,A0}(t+2) in flight.
// WAR: B(t) last read P2(t) < P3(t) stage; A(t) last read P3(t) < P4(t) stage.
// Per phase: {ds_reads; stage(s); [gate]; s_barrier; lgkmcnt(0)+sched_barrier;
//             setprio(1); 16 MFMA; setprio(0); s_barrier}.
// XCD chunking: bm=(blk&7)*4+(blk>>6), bn=(blk>>3)&7 -> 4bm x 8bn per XCD.
// OUT16: y stored i16*256 in TILED layout (coalesced 128B lines):
//   idx = ((((blk*8+w)*4+n)*32 + m*4+j)*64 + lane
template <bool OUT16>
__global__ __launch_bounds__(512, 2) void fpbn_gemm8(
    const unsigned short* __restrict__ xb, const unsigned short* __restrict__ wb,
    const float* __restrict__ bias, short* __restrict__ y16,
    float* __restrict__ yf, float* __restrict__ colsum,
    float* __restrict__ colsumsq) {

    __shared__ unsigned short lds[65536];   // 128 KiB, 8 slots of 8192 elems

    const int t    = threadIdx.x;
    const int lane = t & 63;
    const int w    = t >> 6;        // 0..7
    const int wm   = w >> 2;        // 0..1  (M half of 256)
    const int wn   = w & 3;         // 0..3  (N quarter)

    const int blk  = blockIdx.x;
    const int bm   = (blk & 7) * 4 + (blk >> 6);    // 0..31
    const int bn   = (blk >> 3) & 7;                // 0..7
    const int row0 = bm * 256;
    const int col0 = bn * 256;

    // ---- staging source addresses (linear LDS dest, inverse-swizzled src) ----
    const int roff = t >> 3;                        // row within half: 0..63
    const int colE = ((t & 7) ^ (roff & 7)) * 8;    // swizzle-compensated col (elems)
    const unsigned short* srcA[2] = {
        xb + (size_t)(row0 +   0 + roff) * Kdim + colE,
        xb + (size_t)(row0 + 128 + roff) * Kdim + colE };
    const unsigned short* srcB[2] = {
        wb + (size_t)(col0 +   0 + roff) * Kdim + colE,
        wb + (size_t)(col0 + 128 + roff) * Kdim + colE };
    const int t8 = t * 8;

    // ---- swizzled read-side per-lane constants ----
    const int x3    = lane & 7;
    const int xk    = x3 >> 2;                 // flips kk-select (bit6 of XOR)
    const int xh    = x3 & 3;                  // flips hi-select (bits 4-5)
    const int hi    = lane >> 4;
    const int rb2   = (lane & 15) * 64 + ((hi ^ xh) * 8);
    const int k0off = xk * 32;                 // elem offset of logical kk=0
    const int k1off = 32 - k0off;              // logical kk=1
    const int bnoff = (wn & 1) * 4096;

#define STAGE(BUF_, S_, OP_, HALF_) do {                                      \
        int ss_ = (S_) < NT ? (S_) : (S_) - 2;  /* tail clamp, keeps parity */\
        const unsigned short* sp_ = (OP_ ? srcB : srcA)[HALF_] + ss_ * 64;    \
        unsigned short* dp_ =                                                 \
            &lds[(((BUF_) * 4 + (OP_) * 2 + (HALF_)) << 13) + t8];            \
        gload_lds16(sp_, dp_);                                                \
        gload_lds16(sp_ + (size_t)64 * Kdim, dp_ + 4096);                     \
    } while (0)

#define READA(BUF_, M_, KOFF_) \
    (*(const short8*)&lds[(((BUF_) * 4 + wm) << 13) + rb2 + (M_) * 1024 + (KOFF_)])
#define READB(BUF_, N_, KOFF_) \
    (*(const short8*)&lds[(((BUF_) * 4 + 2 + (wn >> 1)) << 13) + bnoff + rb2 + (N_) * 1024 + (KOFF_)])
#define MFMA_(A_, B_, C_) \
    C_ = __builtin_amdgcn_mfma_f32_16x16x32_bf16(A_, B_, C_, 0, 0, 0)

#define PH_OPEN                                                    \
    __builtin_amdgcn_s_barrier();                                  \
    asm volatile("s_waitcnt lgkmcnt(0)" ::: "memory");             \
    __builtin_amdgcn_sched_barrier(0);                             \
    __builtin_amdgcn_s_setprio(1);

#define PH_CLOSE                                                   \
    __builtin_amdgcn_s_setprio(0);                                 \
    __builtin_amdgcn_s_barrier();

#define GATE_VM6 asm volatile("s_waitcnt vmcnt(6)" ::: "memory")

    f32x4 acc[8][4] = {};

    // prologue: tile0 complete (8 loads) + tile1 B0,B1,A0 (6 loads);
    // gate vmcnt(6) retires all of tile0, leaves tile1's 3 half-tiles.
    STAGE(0, 0, 1, 0); STAGE(0, 0, 1, 1); STAGE(0, 0, 0, 0); STAGE(0, 0, 0, 1);
    STAGE(1, 1, 1, 0); STAGE(1, 1, 1, 1); STAGE(1, 1, 0, 0);
    GATE_VM6;
    __builtin_amdgcn_s_barrier();

// One K-tile = 4 phases. SA1_ stages A1(t+1); SB0_/SB1_ stage B(t+2);
// SA0_ stages A0(t+2); gate vmcnt(6) at P4 only.
#define KTILE(BUF_, SA1_, SB0_, SB1_, SA0_) do {                              \
        /* P1: reads Bf0+Af(12); stage A1(t+1) */                             \
        _Pragma("unroll") for (int n = 0; n < 2; ++n) {                       \
            Bf0[n][0] = READB(BUF_, n, k0off);                                \
            Bf0[n][1] = READB(BUF_, n, k1off); }                              \
        _Pragma("unroll") for (int m = 0; m < 4; ++m) {                       \
            Af[m][0] = READA(BUF_, m, k0off);                                 \
            Af[m][1] = READA(BUF_, m, k1off); }                               \
        SA1_;                                                                 \
        PH_OPEN                                                               \
        _Pragma("unroll") for (int m = 0; m < 4; ++m)                         \
        _Pragma("unroll") for (int n = 0; n < 2; ++n) {                       \
            MFMA_(Af[m][0], Bf0[n][0], acc[m][n]);                            \
            MFMA_(Af[m][1], Bf0[n][1], acc[m][n]); }                          \
        PH_CLOSE                                                              \
        /* P2: reads Bf1(4); no stage */                                      \
        _Pragma("unroll") for (int n = 0; n < 2; ++n) {                       \
            Bf1[n][0] = READB(BUF_, n + 2, k0off);                            \
            Bf1[n][1] = READB(BUF_, n + 2, k1off); }                          \
        PH_OPEN                                                               \
        _Pragma("unroll") for (int m = 0; m < 4; ++m)                         \
        _Pragma("unroll") for (int n = 0; n < 2; ++n) {                       \
            MFMA_(Af[m][0], Bf1[n][0], acc[m][n + 2]);                        \
            MFMA_(Af[m][1], Bf1[n][1], acc[m][n + 2]); }                      \
        PH_CLOSE                                                              \
        /* P3: reads Af2(8); stage B0,B1(t+2) (B(t) reads done at P2) */      \
        _Pragma("unroll") for (int m = 0; m < 4; ++m) {                       \
            Af2[m][0] = READA(BUF_, m + 4, k0off);                            \
            Af2[m][1] = READA(BUF_, m + 4, k1off); }                          \
        SB0_;                                                                 \
        SB1_;                                                                 \
        PH_OPEN                                                               \
        _Pragma("unroll") for (int m = 0; m < 4; ++m)                         \
        _Pragma("unroll") for (int n = 0; n < 2; ++n) {                       \
            MFMA_(Af2[m][0], Bf1[n][0], acc[m + 4][n + 2]);                   \
            MFMA_(Af2[m][1], Bf1[n][1], acc[m + 4][n + 2]); }                 \
        PH_CLOSE                                                              \
        /* P4: no reads (Bf0 regs reused); stage A0(t+2); gate vmcnt(6) */    \
        SA0_;                                                                 \
        GATE_VM6;                                                             \
        PH_OPEN                                                               \
        _Pragma("unroll") for (int m = 0; m < 4; ++m)                         \
        _Pragma("unroll") for (int n = 0; n < 2; ++n) {                       \
            MFMA_(Af2[m][0], Bf0[n][0], acc[m + 4][n]);                       \
            MFMA_(Af2[m][1], Bf0[n][1], acc[m + 4][n]); }                     \
        PH_CLOSE                                                              \
    } while (0)

#pragma unroll 1
    for (int it = 0; it < NT / 2; ++it) {
        const int s0 = 2 * it;
        short8 Af[4][2], Af2[4][2], Bf0[2][2], Bf1[2][2];
        KTILE(0, STAGE(1, s0 + 1, 0, 1),
                 STAGE(0, s0 + 2, 1, 0), STAGE(0, s0 + 2, 1, 1),
                 STAGE(0, s0 + 2, 0, 0));
        KTILE(1, STAGE(0, s0 + 2, 0, 1),
                 STAGE(1, s0 + 3, 1, 0), STAGE(1, s0 + 3, 1, 1),
                 STAGE(1, s0 + 3, 0, 0));
    }
    // drain clamped tail stages before LDS goes out of scope / epilogue
    asm volatile("s_waitcnt vmcnt(0)" ::: "memory");

    // Epilogue. C/D layout: col = lane&15, row = (lane>>4)*4 + j
#pragma unroll
    for (int n = 0; n < 4; ++n) {
        const int col = col0 + wn * 64 + n * 16 + (lane & 15);
        const float qb = fpq(bias[col]);
        float s = 0.0f, s2 = 0.0f;
#pragma unroll
        for (int m = 0; m < 8; ++m) {
            const int rowb = row0 + wm * 128 + m * 16 + ((lane >> 4) * 4);
#pragma unroll
            for (int j = 0; j < 4; ++j) {
                float v = fpq(acc[m][n][j]);
                v = fpq(v + qb);
                if constexpr (OUT16) {
                    // tiled layout: 128B-dense lines
                    size_t idx = ((((size_t)blk * 8 + w) * 4 + n) * 32
                                  + m * 4 + j) * 64 + lane;
                    y16[idx] = (short)(v * 256.0f);
                } else {
                    yf[(size_t)(rowb + j) * Ndim + col] = v;
                }
                s += v;
                s2 += v * v;
            }
        }
        s  += __shfl_xor(s, 16, 64);  s  += __shfl_xor(s, 32, 64);
        s2 += __shfl_xor(s2, 16, 64); s2 += __shfl_xor(s2, 32, 64);
        if (lane < 16) {
            atomicAdd(&colsum[col], s);
            atomicAdd(&colsumsq[col], s2);
        }
    }
#undef STAGE
#undef READA
#undef READB
#undef MFMA_
#undef KTILE
#undef PH_OPEN
#undef PH_CLOSE
#undef GATE_VM6
}

// ---------------------------------------------------------------------------
__global__ void fpbn_finalize(const float* __restrict__ colsum,
                              const float* __restrict__ colsumsq,
                              const float* __restrict__ gamma,
                              const float* __restrict__ beta,
                              float* __restrict__ a, float* __restrict__ b) {
    int i = blockIdx.x * blockDim.x + threadIdx.x;
    if (i < Ndim) {
        float mean = colsum[i] * (1.0f / Mdim);
        float var  = colsumsq[i] * (1.0f / Mdim) - mean * mean;
        float inv  = 1.0f / sqrtf(var + kEps);
        float ai   = gamma[i] * inv;
        a[i] = ai;
        b[i] = beta[i] - mean * ai;
    }
}

// BN apply + final quantize: tiled i16 y -> row-major f32 out.
// Thread g handles row r = g>>8, cols c..c+7 (c = (g&255)*8).
__global__ void fpbn_apply16(const short* __restrict__ y16,
                             float* __restrict__ out,
                             const float* __restrict__ a,
                             const float* __restrict__ b, int ngroups) {
    int tid = blockIdx.x * blockDim.x + threadIdx.x;
    int stride = gridDim.x * blockDim.x;
    for (int g = tid; g < ngroups; g += stride) {
        const int r  = g >> 8;
        const int c  = (g & 255) * 8;
        const int bm = r >> 8, wm = (r >> 7) & 1, m = (r >> 4) & 7,
                  hi = (r >> 2) & 3, j = r & 3;
        const int bn = c >> 8, wn = (c >> 6) & 3, n = (c >> 4) & 3,
                  lane = hi * 16 + (c & 15);
        const int blk = (bm >> 2) | (bn << 3) | ((bm & 3) << 6);
        const int w   = wm * 4 + wn;
        const size_t idx = ((((size_t)blk * 8 + w) * 4 + n) * 32
                            + m * 4 + j) * 64 + lane;
        int4 raw = *(const int4*)(y16 + idx);      // 8 shorts, 16B aligned
        const short* sp = (const short*)&raw;
        float4 a0 = *(const float4*)&a[c], a1 = *(const float4*)&a[c + 4];
        float4 b0 = *(const float4*)&b[c], b1 = *(const float4*)&b[c + 4];
        float4 o0, o1;
        o0.x = fpq(fmaf(a0.x, (float)sp[0] * kInvScale, b0.x));
        o0.y = fpq(fmaf(a0.y, (float)sp[1] * kInvScale, b0.y));
        o0.z = fpq(fmaf(a0.z, (float)sp[2] * kInvScale, b0.z));
        o0.w = fpq(fmaf(a0.w, (float)sp[3] * kInvScale, b0.w));
        o1.x = fpq(fmaf(a1.x, (float)sp[4] * kInvScale, b1.x));
        o1.y = fpq(fmaf(a1.y, (float)sp[5] * kInvScale, b1.y));
        o1.z = fpq(fmaf(a1.z, (float)sp[6] * kInvScale, b1.z));
        o1.w = fpq(fmaf(a1.w, (float)sp[7] * kInvScale, b1.w));
        float* op = out + (size_t)r * Ndim + c;
        ((float4*)op)[0] = o0;
        ((float4*)op)[1] = o1;
    }
}

// BN apply + final quantize, f32 y in-place (fallback path)
__global__ void fpbn_apply(float* __restrict__ y,
                           const float* __restrict__ a,
                           const float* __restrict__ b, int n4) {
    int i = blockIdx.x * blockDim.x + threadIdx.x;
    int stride = gridDim.x * blockDim.x;
    for (; i < n4; i += stride) {
        float4 v = ((float4*)y)[i];
        int cb = (i * 4) & (Ndim - 1);
        float4 av = *(const float4*)&a[cb];
        float4 bv = *(const float4*)&b[cb];
        v.x = fpq(fmaf(av.x, v.x, bv.x));
        v.y = fpq(fmaf(av.y, v.y, bv.y));
        v.z = fpq(fmaf(av.z, v.z, bv.z));
        v.w = fpq(fmaf(av.w, v.w, bv.w));
        ((float4*)y)[i] = v;
    }
}

// ---------------------------------------------------------------------------
extern "C" void kernel_launch(void* const* d_in, const int* in_sizes, int n_in,
                              void* d_out, int out_size, void* d_ws, size_t ws_size,
                              hipStream_t stream) {
    const float* x      = (const float*)d_in[0];
    const float* weight = (const float*)d_in[1];
    const float* bias   = (const float*)d_in[2];
    const float* gamma  = (const float*)d_in[3];
    const float* beta   = (const float*)d_in[4];
    float* out = (float*)d_out;

    // ws: wb bf16 [8MB] | stats [64KB] | xb bf16 [32MB] | y16 [32MB optional]
    char* ws = (char*)d_ws;
    unsigned short* wb = (unsigned short*)ws;
    const size_t wbBytes = (size_t)Ndim * Kdim * 2;
    float* colsum   = (float*)(ws + wbBytes);
    float* colsumsq = colsum + Ndim;
    float* aArr     = colsum + 2 * Ndim;
    float* bArr     = colsum + 3 * Ndim;
    const size_t xbOff = wbBytes + 65536;
    unsigned short* xb = (unsigned short*)(ws + xbOff);
    const size_t xbBytes  = (size_t)Mdim * Kdim * 2;
    const size_t y16Off   = xbOff + xbBytes;
    short* y16 = (short*)(ws + y16Off);
    const size_t need16 = y16Off + (size_t)Mdim * Ndim * 2;   // ~72.1 MB

    fpbn_prep<<<3072, 256, 0, stream>>>(weight, wb, x, xb, colsum);

    if (ws_size >= need16) {
        fpbn_gemm8<true><<<(Mdim / 256) * (Ndim / 256), 512, 0, stream>>>(
            xb, wb, bias, y16, nullptr, colsum, colsumsq);
        fpbn_finalize<<<(Ndim + 255) / 256, 256, 0, stream>>>(
            colsum, colsumsq, gamma, beta, aArr, bArr);
        fpbn_apply16<<<2048, 256, 0, stream>>>(y16, out, aArr, bArr,
                                               Mdim * Ndim / 8);
    } else {
        fpbn_gemm8<false><<<(Mdim / 256) * (Ndim / 256), 512, 0, stream>>>(
            xb, wb, bias, nullptr, out, colsum, colsumsq);
        fpbn_finalize<<<(Ndim + 255) / 256, 256, 0, stream>>>(
            colsum, colsumsq, gamma, beta, aArr, bArr);
        fpbn_apply<<<2048, 256, 0, stream>>>(out, aArr, bArr, Mdim * Ndim / 4);
    }
}

// Round 10
// 214.019 us; speedup vs baseline: 1.0751x; 1.0071x over previous
//
#include <hip/hip_runtime.h>
#include <hip/hip_bf16.h>

// Problem dims (fixed by setup_inputs)
#define Mdim 8192
#define Ndim 2048
#define Kdim 2048
#define NT   32      // number of K-tiles (Kdim / 64)

constexpr float kMin = -128.0f;
constexpr float kMax = 127.99609375f;
constexpr float kScale = 256.0f;
constexpr float kInvScale = 1.0f / 256.0f;
constexpr float kEps = 1e-5f;

typedef __attribute__((ext_vector_type(8))) short short8;
typedef __attribute__((ext_vector_type(4))) float f32x4;

__device__ __forceinline__ float fpq(float x) {
    x = fminf(fmaxf(x, kMin), kMax);
    return rintf(x * kScale) * kInvScale;   // round-half-to-even, matches jnp.round
}

__device__ __forceinline__ unsigned short f2bf(float f) {
    union { __hip_bfloat16 h; unsigned short u; } cv;
    cv.h = __float2bfloat16(f);             // RNE
    return cv.u;
}

__device__ __forceinline__ void gload_lds16(const void* g, void* l) {
    __builtin_amdgcn_global_load_lds(
        (const __attribute__((address_space(1))) unsigned int*)g,
        (__attribute__((address_space(3))) unsigned int*)l,
        16, 0, 0);
}

// ---------------------------------------------------------------------------
// Fused prep: zero stats (block 0), quantize w -> bf16 (blocks 0..1023),
// convert x -> bf16 (blocks 1024..3071).
__global__ void fpbn_prep(const float* __restrict__ w,
                          unsigned short* __restrict__ wb,
                          const float* __restrict__ x,
                          unsigned short* __restrict__ xb,
                          float* __restrict__ stats) {
    const int b = blockIdx.x;
    if (b == 0) {
        float4 z = {0.f, 0.f, 0.f, 0.f};
        for (int i = threadIdx.x; i < 1024; i += 256)   // 4096 floats
            ((float4*)stats)[i] = z;
    }
    if (b < 1024) {
        const int n4 = Ndim * Kdim / 4;
        for (int i = b * 256 + threadIdx.x; i < n4; i += 1024 * 256) {
            float4 v = ((const float4*)w)[i];
            ushort4 o;
            o.x = f2bf(fpq(v.x));
            o.y = f2bf(fpq(v.y));
            o.z = f2bf(fpq(v.z));
            o.w = f2bf(fpq(v.w));
            ((ushort4*)wb)[i] = o;
        }
    } else {
        const int n8 = Mdim * Kdim / 8;
        for (int i = (b - 1024) * 256 + threadIdx.x; i < n8; i += 2048 * 256) {
            float4 p = ((const float4*)x)[2 * i];
            float4 q = ((const float4*)x)[2 * i + 1];
            uint4 o;
            o.x = (unsigned)f2bf(p.x) | ((unsigned)f2bf(p.y) << 16);
            o.y = (unsigned)f2bf(p.z) | ((unsigned)f2bf(p.w) << 16);
            o.z = (unsigned)f2bf(q.x) | ((unsigned)f2bf(q.y) << 16);
            o.w = (unsigned)f2bf(q.z) | ((unsigned)f2bf(q.w) << 16);
            ((uint4*)xb)[i] = o;
        }
    }
}

// ---------------------------------------------------------------------------
// 256x256x(BK=64) bf16 MFMA GEMM; 8-phase skeleton with ds_read∥MFMA
// interleave: each phase's reads are issued INSIDE the previous phase's MFMA
// window (different dest regs -> compiler interleaves; drained by the next
// PH_OPEN's lgkmcnt(0) after a full MFMA phase).
//
// Clusters per tile t (A-regs ping-pong X/Y per tile; B0r/B1r fixed):
//  P1: C1=A0·B0->acc[0-3][0-1];  window: read A1 (rows 4-7)      | close: SA1(t+1)
//  P2: C2=A1·B0->acc[4-7][0-1];  window: read B1 (N 2,3)         |
//  P3: C3=A1·B1->acc[4-7][2-3];  window: none | close: SB0,SB1,SA0(t+2); GATE vm6
//  P4: C4=A0·B1->acc[0-3][2-3];  window: read t+1's A0 (into A1-regs) + B0
// Gate@P3(t) retires everything through SA1(t+1) (all of t+1), leaves
// {SB0,SB1,SA0}(t+2)=6 in flight -> P4's cross-tile reads are safe after its
// barrier. WAR: every overwritten slot's reads drained >=1 phase earlier.
// XCD chunking: bm=(blk&7)*4+(blk>>6), bn=(blk>>3)&7 -> 4bm x 8bn per XCD.
// OUT16: y stored i16*256 in TILED layout (coalesced 128B lines).
template <bool OUT16>
__global__ __launch_bounds__(512, 2) void fpbn_gemm8(
    const unsigned short* __restrict__ xb, const unsigned short* __restrict__ wb,
    const float* __restrict__ bias, short* __restrict__ y16,
    float* __restrict__ yf, float* __restrict__ colsum,
    float* __restrict__ colsumsq) {

    __shared__ unsigned short lds[65536];   // 128 KiB, 8 slots of 8192 elems

    const int t    = threadIdx.x;
    const int lane = t & 63;
    const int w    = t >> 6;        // 0..7
    const int wm   = w >> 2;        // 0..1  (M half of 256)
    const int wn   = w & 3;         // 0..3  (N quarter)

    const int blk  = blockIdx.x;
    const int bm   = (blk & 7) * 4 + (blk >> 6);    // 0..31
    const int bn   = (blk >> 3) & 7;                // 0..7
    const int row0 = bm * 256;
    const int col0 = bn * 256;

    // ---- staging source addresses (linear LDS dest, inverse-swizzled src) ----
    const int roff = t >> 3;                        // row within half: 0..63
    const int colE = ((t & 7) ^ (roff & 7)) * 8;    // swizzle-compensated col (elems)
    const unsigned short* srcA[2] = {
        xb + (size_t)(row0 +   0 + roff) * Kdim + colE,
        xb + (size_t)(row0 + 128 + roff) * Kdim + colE };
    const unsigned short* srcB[2] = {
        wb + (size_t)(col0 +   0 + roff) * Kdim + colE,
        wb + (size_t)(col0 + 128 + roff) * Kdim + colE };
    const int t8 = t * 8;

    // ---- swizzled read-side per-lane constants ----
    const int x3    = lane & 7;
    const int xk    = x3 >> 2;                 // flips kk-select (bit6 of XOR)
    const int xh    = x3 & 3;                  // flips hi-select (bits 4-5)
    const int hi    = lane >> 4;
    const int rb2   = (lane & 15) * 64 + ((hi ^ xh) * 8);
    const int k0off = xk * 32;                 // elem offset of logical kk=0
    const int k1off = 32 - k0off;              // logical kk=1
    const int bnoff = (wn & 1) * 4096;

#define STAGE(BUF_, S_, OP_, HALF_) do {                                      \
        int ss_ = (S_) < NT ? (S_) : (S_) - 2;  /* tail clamp, keeps parity */\
        const unsigned short* sp_ = (OP_ ? srcB : srcA)[HALF_] + ss_ * 64;    \
        unsigned short* dp_ =                                                 \
            &lds[(((BUF_) * 4 + (OP_) * 2 + (HALF_)) << 13) + t8];            \
        gload_lds16(sp_, dp_);                                                \
        gload_lds16(sp_ + (size_t)64 * Kdim, dp_ + 4096);                     \
    } while (0)

#define READA(BUF_, M_, KOFF_) \
    (*(const short8*)&lds[(((BUF_) * 4 + wm) << 13) + rb2 + (M_) * 1024 + (KOFF_)])
#define READB(BUF_, N_, KOFF_) \
    (*(const short8*)&lds[(((BUF_) * 4 + 2 + (wn >> 1)) << 13) + bnoff + rb2 + (N_) * 1024 + (KOFF_)])
#define MFMA_(A_, B_, C_) \
    C_ = __builtin_amdgcn_mfma_f32_16x16x32_bf16(A_, B_, C_, 0, 0, 0)

#define PH_OPEN                                                    \
    __builtin_amdgcn_s_barrier();                                  \
    asm volatile("s_waitcnt lgkmcnt(0)" ::: "memory");             \
    __builtin_amdgcn_sched_barrier(0);                             \
    __builtin_amdgcn_s_setprio(1);

#define PH_CLOSE                                                   \
    __builtin_amdgcn_s_setprio(0);                                 \
    __builtin_amdgcn_s_barrier();

#define GATE_VM6 asm volatile("s_waitcnt vmcnt(6)" ::: "memory")

    f32x4 acc[8][4] = {};

    // prologue: tile0 complete (8 loads) + tile1 B0,B1,A0 (6 loads);
    // gate vmcnt(6) retires tile0; barrier; preload tile0's A0->X, B0->B0r.
    STAGE(0, 0, 0, 0); STAGE(0, 0, 0, 1); STAGE(0, 0, 1, 0); STAGE(0, 0, 1, 1);
    STAGE(1, 1, 1, 0); STAGE(1, 1, 1, 1); STAGE(1, 1, 0, 0);
    GATE_VM6;
    __builtin_amdgcn_s_barrier();

    short8 X[4][2], Y[4][2], B0r[2][2], B1r[2][2];
#pragma unroll
    for (int m = 0; m < 4; ++m) {
        X[m][0] = READA(0, m, k0off);
        X[m][1] = READA(0, m, k1off);
    }
#pragma unroll
    for (int n = 0; n < 2; ++n) {
        B0r[n][0] = READB(0, n, k0off);
        B0r[n][1] = READB(0, n, k1off);
    }

// One K-tile = 4 phases; reads ride inside the MFMA windows.
#define KTILE(BUF_, A0_, A1_, SA1_, SB0_, SB1_, SA0_) do {                    \
        /* P1: C1 = A0·B0; window: read A1 (this tile, rows 4-7) */           \
        PH_OPEN                                                               \
        _Pragma("unroll") for (int m = 0; m < 4; ++m)                         \
        _Pragma("unroll") for (int n = 0; n < 2; ++n) {                       \
            MFMA_(A0_[m][0], B0r[n][0], acc[m][n]);                           \
            MFMA_(A0_[m][1], B0r[n][1], acc[m][n]); }                         \
        _Pragma("unroll") for (int m = 0; m < 4; ++m) {                       \
            A1_[m][0] = READA(BUF_, m + 4, k0off);                            \
            A1_[m][1] = READA(BUF_, m + 4, k1off); }                          \
        PH_CLOSE                                                              \
        SA1_;                                                                 \
        /* P2: C2 = A1·B0; window: read B1 (this tile, N 2,3) */              \
        PH_OPEN                                                               \
        _Pragma("unroll") for (int m = 0; m < 4; ++m)                         \
        _Pragma("unroll") for (int n = 0; n < 2; ++n) {                       \
            MFMA_(A1_[m][0], B0r[n][0], acc[m + 4][n]);                       \
            MFMA_(A1_[m][1], B0r[n][1], acc[m + 4][n]); }                     \
        _Pragma("unroll") for (int n = 0; n < 2; ++n) {                       \
            B1r[n][0] = READB(BUF_, n + 2, k0off);                            \
            B1r[n][1] = READB(BUF_, n + 2, k1off); }                          \
        PH_CLOSE                                                              \
        /* P3: C3 = A1·B1; close: stage t+2 halves + gate vm6 */              \
        PH_OPEN                                                               \
        _Pragma("unroll") for (int m = 0; m < 4; ++m)                         \
        _Pragma("unroll") for (int n = 0; n < 2; ++n) {                       \
            MFMA_(A1_[m][0], B1r[n][0], acc[m + 4][n + 2]);                   \
            MFMA_(A1_[m][1], B1r[n][1], acc[m + 4][n + 2]); }                 \
        PH_CLOSE                                                              \
        SB0_; SB1_; SA0_;                                                     \
        GATE_VM6;                                                             \
        /* P4: C4 = A0·B1; window: t+1's A0 -> A1-regs, t+1's B0 -> B0r */    \
        PH_OPEN                                                               \
        _Pragma("unroll") for (int m = 0; m < 4; ++m)                         \
        _Pragma("unroll") for (int n = 0; n < 2; ++n) {                       \
            MFMA_(A0_[m][0], B1r[n][0], acc[m][n + 2]);                       \
            MFMA_(A0_[m][1], B1r[n][1], acc[m][n + 2]); }                     \
        _Pragma("unroll") for (int m = 0; m < 4; ++m) {                       \
            A1_[m][0] = READA((BUF_) ^ 1, m, k0off);                          \
            A1_[m][1] = READA((BUF_) ^ 1, m, k1off); }                        \
        _Pragma("unroll") for (int n = 0; n < 2; ++n) {                       \
            B0r[n][0] = READB((BUF_) ^ 1, n, k0off);                          \
            B0r[n][1] = READB((BUF_) ^ 1, n, k1off); }                        \
        PH_CLOSE                                                              \
    } while (0)

#pragma unroll 1
    for (int it = 0; it < NT / 2; ++it) {
        const int s0 = 2 * it;
        KTILE(0, X, Y, STAGE(1, s0 + 1, 0, 1),
                 STAGE(0, s0 + 2, 1, 0), STAGE(0, s0 + 2, 1, 1),
                 STAGE(0, s0 + 2, 0, 0));
        KTILE(1, Y, X, STAGE(0, s0 + 2, 0, 1),
                 STAGE(1, s0 + 3, 1, 0), STAGE(1, s0 + 3, 1, 1),
                 STAGE(1, s0 + 3, 0, 0));
    }
    // drain remaining staged loads before epilogue
    asm volatile("s_waitcnt vmcnt(0)" ::: "memory");

    // Epilogue. C/D layout: col = lane&15, row = (lane>>4)*4 + j
#pragma unroll
    for (int n = 0; n < 4; ++n) {
        const int col = col0 + wn * 64 + n * 16 + (lane & 15);
        const float qb = fpq(bias[col]);
        float s = 0.0f, s2 = 0.0f;
#pragma unroll
        for (int m = 0; m < 8; ++m) {
            const int rowb = row0 + wm * 128 + m * 16 + ((lane >> 4) * 4);
#pragma unroll
            for (int j = 0; j < 4; ++j) {
                float v = fpq(acc[m][n][j]);
                v = fpq(v + qb);
                if constexpr (OUT16) {
                    // tiled layout: 128B-dense lines
                    size_t idx = ((((size_t)blk * 8 + w) * 4 + n) * 32
                                  + m * 4 + j) * 64 + lane;
                    y16[idx] = (short)(v * 256.0f);
                } else {
                    yf[(size_t)(rowb + j) * Ndim + col] = v;
                }
                s += v;
                s2 += v * v;
            }
        }
        s  += __shfl_xor(s, 16, 64);  s  += __shfl_xor(s, 32, 64);
        s2 += __shfl_xor(s2, 16, 64); s2 += __shfl_xor(s2, 32, 64);
        if (lane < 16) {
            atomicAdd(&colsum[col], s);
            atomicAdd(&colsumsq[col], s2);
        }
    }
#undef STAGE
#undef READA
#undef READB
#undef MFMA_
#undef KTILE
#undef PH_OPEN
#undef PH_CLOSE
#undef GATE_VM6
}

// ---------------------------------------------------------------------------
__global__ void fpbn_finalize(const float* __restrict__ colsum,
                              const float* __restrict__ colsumsq,
                              const float* __restrict__ gamma,
                              const float* __restrict__ beta,
                              float* __restrict__ a, float* __restrict__ b) {
    int i = blockIdx.x * blockDim.x + threadIdx.x;
    if (i < Ndim) {
        float mean = colsum[i] * (1.0f / Mdim);
        float var  = colsumsq[i] * (1.0f / Mdim) - mean * mean;
        float inv  = 1.0f / sqrtf(var + kEps);
        float ai   = gamma[i] * inv;
        a[i] = ai;
        b[i] = beta[i] - mean * ai;
    }
}

// BN apply + final quantize: tiled i16 y -> row-major f32 out.
// Thread g handles row r = g>>8, cols c..c+7 (c = (g&255)*8).
__global__ void fpbn_apply16(const short* __restrict__ y16,
                             float* __restrict__ out,
                             const float* __restrict__ a,
                             const float* __restrict__ b, int ngroups) {
    int tid = blockIdx.x * blockDim.x + threadIdx.x;
    int stride = gridDim.x * blockDim.x;
    for (int g = tid; g < ngroups; g += stride) {
        const int r  = g >> 8;
        const int c  = (g & 255) * 8;
        const int bm = r >> 8, wm = (r >> 7) & 1, m = (r >> 4) & 7,
                  hi = (r >> 2) & 3, j = r & 3;
        const int bn = c >> 8, wn = (c >> 6) & 3, n = (c >> 4) & 3,
                  lane = hi * 16 + (c & 15);
        const int blk = (bm >> 2) | (bn << 3) | ((bm & 3) << 6);
        const int w   = wm * 4 + wn;
        const size_t idx = ((((size_t)blk * 8 + w) * 4 + n) * 32
                            + m * 4 + j) * 64 + lane;
        int4 raw = *(const int4*)(y16 + idx);      // 8 shorts, 16B aligned
        const short* sp = (const short*)&raw;
        float4 a0 = *(const float4*)&a[c], a1 = *(const float4*)&a[c + 4];
        float4 b0 = *(const float4*)&b[c], b1 = *(const float4*)&b[c + 4];
        float4 o0, o1;
        o0.x = fpq(fmaf(a0.x, (float)sp[0] * kInvScale, b0.x));
        o0.y = fpq(fmaf(a0.y, (float)sp[1] * kInvScale, b0.y));
        o0.z = fpq(fmaf(a0.z, (float)sp[2] * kInvScale, b0.z));
        o0.w = fpq(fmaf(a0.w, (float)sp[3] * kInvScale, b0.w));
        o1.x = fpq(fmaf(a1.x, (float)sp[4] * kInvScale, b1.x));
        o1.y = fpq(fmaf(a1.y, (float)sp[5] * kInvScale, b1.y));
        o1.z = fpq(fmaf(a1.z, (float)sp[6] * kInvScale, b1.z));
        o1.w = fpq(fmaf(a1.w, (float)sp[7] * kInvScale, b1.w));
        float* op = out + (size_t)r * Ndim + c;
        ((float4*)op)[0] = o0;
        ((float4*)op)[1] = o1;
    }
}

// BN apply + final quantize, f32 y in-place (fallback path)
__global__ void fpbn_apply(float* __restrict__ y,
                           const float* __restrict__ a,
                           const float* __restrict__ b, int n4) {
    int i = blockIdx.x * blockDim.x + threadIdx.x;
    int stride = gridDim.x * blockDim.x;
    for (; i < n4; i += stride) {
        float4 v = ((float4*)y)[i];
        int cb = (i * 4) & (Ndim - 1);
        float4 av = *(const float4*)&a[cb];
        float4 bv = *(const float4*)&b[cb];
        v.x = fpq(fmaf(av.x, v.x, bv.x));
        v.y = fpq(fmaf(av.y, v.y, bv.y));
        v.z = fpq(fmaf(av.z, v.z, bv.z));
        v.w = fpq(fmaf(av.w, v.w, bv.w));
        ((float4*)y)[i] = v;
    }
}

// ---------------------------------------------------------------------------
extern "C" void kernel_launch(void* const* d_in, const int* in_sizes, int n_in,
                              void* d_out, int out_size, void* d_ws, size_t ws_size,
                              hipStream_t stream) {
    const float* x      = (const float*)d_in[0];
    const float* weight = (const float*)d_in[1];
    const float* bias   = (const float*)d_in[2];
    const float* gamma  = (const float*)d_in[3];
    const float* beta   = (const float*)d_in[4];
    float* out = (float*)d_out;

    // ws: wb bf16 [8MB] | stats [64KB] | xb bf16 [32MB] | y16 [32MB optional]
    char* ws = (char*)d_ws;
    unsigned short* wb = (unsigned short*)ws;
    const size_t wbBytes = (size_t)Ndim * Kdim * 2;
    float* colsum   = (float*)(ws + wbBytes);
    float* colsumsq = colsum + Ndim;
    float* aArr     = colsum + 2 * Ndim;
    float* bArr     = colsum + 3 * Ndim;
    const size_t xbOff = wbBytes + 65536;
    unsigned short* xb = (unsigned short*)(ws + xbOff);
    const size_t xbBytes  = (size_t)Mdim * Kdim * 2;
    const size_t y16Off   = xbOff + xbBytes;
    short* y16 = (short*)(ws + y16Off);
    const size_t need16 = y16Off + (size_t)Mdim * Ndim * 2;   // ~72.1 MB

    fpbn_prep<<<3072, 256, 0, stream>>>(weight, wb, x, xb, colsum);

    if (ws_size >= need16) {
        fpbn_gemm8<true><<<(Mdim / 256) * (Ndim / 256), 512, 0, stream>>>(
            xb, wb, bias, y16, nullptr, colsum, colsumsq);
        fpbn_finalize<<<(Ndim + 255) / 256, 256, 0, stream>>>(
            colsum, colsumsq, gamma, beta, aArr, bArr);
        fpbn_apply16<<<2048, 256, 0, stream>>>(y16, out, aArr, bArr,
                                               Mdim * Ndim / 8);
    } else {
        fpbn_gemm8<false><<<(Mdim / 256) * (Ndim / 256), 512, 0, stream>>>(
            xb, wb, bias, nullptr, out, colsum, colsumsq);
        fpbn_finalize<<<(Ndim + 255) / 256, 256, 0, stream>>>(
            colsum, colsumsq, gamma, beta, aArr, bArr);
        fpbn_apply<<<2048, 256, 0, stream>>>(out, aArr, bArr, Mdim * Ndim / 4);
    }
}